// Round 1
// baseline (332.202 us; speedup 1.0000x reference)
//
#include <hip/hip_runtime.h>

// ---------------------------------------------------------------------------
// SortNet: 3-layer 1x1-conv MLP (64->64->16->1) with training-mode BatchNorm
// + ReLU, per-batch top-64 over N, gather of input + score.
//
// Pipeline (6 launches, all deterministic, fixed-order reductions):
//   k_prep     : transpose w0 (64x64) and w1 (16x64) for wave-uniform s_loads
//   k_stat0    : y0 = w0@sv + b0, per-channel sum/sumsq partials (recompute pass)
//   k_reduce0  : finalize scale0/shift0  (scale = g*rsqrt(var+eps), shift = bt - mu*scale)
//   k_layer01  : recompute y0, bn0+relu -> h0, y1 = w1@h0 + b1, write y1, stats1 partials
//   k_reduce1  : finalize scale1/shift1
//   k_layer2   : h1 = relu(bn1(y1)), y2 = w2@h1 + b2, write y2, stats2 partials
//   k_topk     : finalize stats2 (per-block, deterministic), rank by raw y2
//                (monotone since scale2>0), 64 rounds of exact argmax with
//                jax tie-break (lower index wins), gather feat + idx.
// ---------------------------------------------------------------------------

constexpr int   B_   = 16;
constexpr int   F_   = 64;
constexpr int   N_   = 32768;
constexpr int   C0_  = 64;
constexpr int   C1_  = 16;
constexpr int   K_   = 64;            // TOP_K
constexpr long long S_ = (long long)B_ * N_;   // 524288
constexpr float EPS_ = 1e-5f;

constexpr int NB0 = 1024;    // k_stat0 blocks
constexpr int NB1 = 2048;    // k_layer01 blocks
constexpr int NB2 = 2048;    // k_layer2 blocks (1 tile of 256 positions each)
constexpr int T64 = 8192;    // number of 64-position tiles (S/64)

// --------------------------- k_prep ----------------------------------------
__global__ __launch_bounds__(256) void k_prep(const float* __restrict__ w0,
                                              const float* __restrict__ w1,
                                              float* __restrict__ w0T,
                                              float* __restrict__ w1T) {
  int t = threadIdx.x;
  for (int e = t; e < 64 * 64; e += 256) {
    int o = e >> 6, f = e & 63;
    w0T[f * 64 + o] = w0[e];          // w0T[f][o] = w0[o][f]
  }
  for (int e = t; e < 16 * 64; e += 256) {
    int o = e >> 6, c = e & 63;
    w1T[c * 16 + o] = w1[e];          // w1T[c][o] = w1[o][c]
  }
}

// --------------------------- k_stat0 ---------------------------------------
// Each block: grid-stride over 64-position tiles. Thread (p = t&63, cg = t>>6)
// computes y0 for 16 channels of its position; accumulates sum/sumsq.
__global__ __launch_bounds__(256) void k_stat0(const float* __restrict__ sv,
                                               const float* __restrict__ w0T,
                                               const float* __restrict__ b0,
                                               float* __restrict__ p0) {
  __shared__ float svt[64][64];
  const int t  = threadIdx.x;
  const int p  = t & 63;
  const int cg = __builtin_amdgcn_readfirstlane(t >> 6);  // wave-uniform

  float bb[16];
#pragma unroll
  for (int j = 0; j < 16; ++j) bb[j] = b0[cg * 16 + j];

  float s1[16], s2[16];
#pragma unroll
  for (int j = 0; j < 16; ++j) { s1[j] = 0.f; s2[j] = 0.f; }

  for (int tile = blockIdx.x; tile < T64; tile += NB0) {
    const int b  = tile >> 9;             // 512 tiles per batch
    const int n0 = (tile & 511) << 6;
    const float* src = sv + ((long long)b * 64) * N_ + n0;
    __syncthreads();
#pragma unroll
    for (int q = 0; q < 4; ++q) {
      int e = t + q * 256;                // 1024 float4 per tile
      int f = e >> 4, c4 = (e & 15) << 2;
      *(float4*)&svt[f][c4] = *(const float4*)(src + (long long)f * N_ + c4);
    }
    __syncthreads();

    float y[16];
#pragma unroll
    for (int j = 0; j < 16; ++j) y[j] = bb[j];
    for (int f = 0; f < 64; ++f) {
      float s = svt[f][p];
      const float* wr = w0T + f * 64 + cg * 16;   // wave-uniform -> s_load
#pragma unroll
      for (int j = 0; j < 16; ++j) y[j] = fmaf(wr[j], s, y[j]);
    }
#pragma unroll
    for (int j = 0; j < 16; ++j) {
      s1[j] += y[j];
      s2[j] = fmaf(y[j], y[j], s2[j]);
    }
  }

#pragma unroll
  for (int j = 0; j < 16; ++j) {
#pragma unroll
    for (int off = 32; off; off >>= 1) {
      s1[j] += __shfl_down(s1[j], off, 64);
      s2[j] += __shfl_down(s2[j], off, 64);
    }
  }
  if (p == 0) {
    float* dst = p0 + (long long)blockIdx.x * 128;
#pragma unroll
    for (int j = 0; j < 16; ++j) {
      dst[cg * 16 + j]      = s1[j];
      dst[64 + cg * 16 + j] = s2[j];
    }
  }
}

// --------------------------- k_reduce0 -------------------------------------
__global__ __launch_bounds__(128) void k_reduce0(const float* __restrict__ p0,
                                                 const float* __restrict__ g,
                                                 const float* __restrict__ bt,
                                                 float* __restrict__ st) {
  __shared__ float l[128];
  int j = threadIdx.x;
  float a0 = 0.f, a1 = 0.f, a2 = 0.f, a3 = 0.f;
  for (int i = 0; i < NB0; i += 4) {
    a0 += p0[(long long)(i + 0) * 128 + j];
    a1 += p0[(long long)(i + 1) * 128 + j];
    a2 += p0[(long long)(i + 2) * 128 + j];
    a3 += p0[(long long)(i + 3) * 128 + j];
  }
  l[j] = (a0 + a1) + (a2 + a3);
  __syncthreads();
  if (j < 64) {
    const float inv = 1.f / (float)S_;
    float mean = l[j] * inv;
    float ex2  = l[64 + j] * inv;
    float var  = ex2 - mean * mean;
    float sc   = g[j] * rsqrtf(var + EPS_);
    st[j]      = sc;
    st[64 + j] = bt[j] - mean * sc;
  }
}

// --------------------------- k_layer01 -------------------------------------
__global__ __launch_bounds__(256) void k_layer01(const float* __restrict__ sv,
                                                 const float* __restrict__ w0T,
                                                 const float* __restrict__ b0,
                                                 const float* __restrict__ st0,
                                                 const float* __restrict__ w1T,
                                                 const float* __restrict__ b1,
                                                 float* __restrict__ y1,
                                                 float* __restrict__ p1) {
  __shared__ float svt[64][64];
  __shared__ float h0[64][64];
  const int t  = threadIdx.x;
  const int p  = t & 63;
  const int cg = __builtin_amdgcn_readfirstlane(t >> 6);

  float bb[16], sc[16], sh[16];
#pragma unroll
  for (int j = 0; j < 16; ++j) {
    bb[j] = b0[cg * 16 + j];
    sc[j] = st0[cg * 16 + j];
    sh[j] = st0[64 + cg * 16 + j];
  }
  float bb1[4];
#pragma unroll
  for (int j = 0; j < 4; ++j) bb1[j] = b1[cg * 4 + j];

  float s1[4], s2[4];
#pragma unroll
  for (int j = 0; j < 4; ++j) { s1[j] = 0.f; s2[j] = 0.f; }

  for (int tile = blockIdx.x; tile < T64; tile += NB1) {
    const int b  = tile >> 9;
    const int n0 = (tile & 511) << 6;
    const float* src = sv + ((long long)b * 64) * N_ + n0;
    __syncthreads();
#pragma unroll
    for (int q = 0; q < 4; ++q) {
      int e = t + q * 256;
      int f = e >> 4, c4 = (e & 15) << 2;
      *(float4*)&svt[f][c4] = *(const float4*)(src + (long long)f * N_ + c4);
    }
    __syncthreads();

    float y[16];
#pragma unroll
    for (int j = 0; j < 16; ++j) y[j] = bb[j];
    for (int f = 0; f < 64; ++f) {
      float s = svt[f][p];
      const float* wr = w0T + f * 64 + cg * 16;
#pragma unroll
      for (int j = 0; j < 16; ++j) y[j] = fmaf(wr[j], s, y[j]);
    }
#pragma unroll
    for (int j = 0; j < 16; ++j) {
      float h = fmaf(y[j], sc[j], sh[j]);
      h0[cg * 16 + j][p] = h > 0.f ? h : 0.f;
    }
    __syncthreads();

    float z[4];
#pragma unroll
    for (int j = 0; j < 4; ++j) z[j] = bb1[j];
    for (int f = 0; f < 64; ++f) {
      float h = h0[f][p];
      const float* wr = w1T + f * 16 + cg * 4;
#pragma unroll
      for (int j = 0; j < 4; ++j) z[j] = fmaf(wr[j], h, z[j]);
    }
#pragma unroll
    for (int j = 0; j < 4; ++j) {
      s1[j] += z[j];
      s2[j] = fmaf(z[j], z[j], s2[j]);
      y1[((long long)b * 16 + cg * 4 + j) * N_ + n0 + p] = z[j];
    }
  }

#pragma unroll
  for (int j = 0; j < 4; ++j) {
#pragma unroll
    for (int off = 32; off; off >>= 1) {
      s1[j] += __shfl_down(s1[j], off, 64);
      s2[j] += __shfl_down(s2[j], off, 64);
    }
  }
  if (p == 0) {
    float* dst = p1 + (long long)blockIdx.x * 32;
#pragma unroll
    for (int j = 0; j < 4; ++j) {
      dst[cg * 4 + j]      = s1[j];
      dst[16 + cg * 4 + j] = s2[j];
    }
  }
}

// --------------------------- k_reduce1 -------------------------------------
__global__ __launch_bounds__(64) void k_reduce1(const float* __restrict__ p1,
                                                const float* __restrict__ g,
                                                const float* __restrict__ bt,
                                                float* __restrict__ st) {
  __shared__ float l[32];
  int j = threadIdx.x;
  if (j < 32) {
    float a0 = 0.f, a1 = 0.f, a2 = 0.f, a3 = 0.f;
    for (int i = 0; i < NB1; i += 4) {
      a0 += p1[(long long)(i + 0) * 32 + j];
      a1 += p1[(long long)(i + 1) * 32 + j];
      a2 += p1[(long long)(i + 2) * 32 + j];
      a3 += p1[(long long)(i + 3) * 32 + j];
    }
    l[j] = (a0 + a1) + (a2 + a3);
  }
  __syncthreads();
  if (j < 16) {
    const float inv = 1.f / (float)S_;
    float mean = l[j] * inv;
    float ex2  = l[16 + j] * inv;
    float var  = ex2 - mean * mean;
    float sc   = g[j] * rsqrtf(var + EPS_);
    st[j]      = sc;
    st[16 + j] = bt[j] - mean * sc;
  }
}

// --------------------------- k_layer2 --------------------------------------
__global__ __launch_bounds__(256) void k_layer2(const float* __restrict__ y1,
                                                const float* __restrict__ st1,
                                                const float* __restrict__ w2,
                                                const float* __restrict__ b2,
                                                float* __restrict__ y2,
                                                float* __restrict__ p2) {
  __shared__ float yt[16][256];
  __shared__ float ls[4], lq[4];
  const int t    = threadIdx.x;
  const int tile = blockIdx.x;          // 2048 tiles of 256 positions
  const int b    = tile >> 7;           // 128 tiles per batch
  const int n0   = (tile & 127) << 8;
  const float* src = y1 + ((long long)b * 16) * N_ + n0;
#pragma unroll
  for (int q = 0; q < 4; ++q) {
    int e = t + q * 256;                // 1024 float4
    int c = e >> 6, c4 = (e & 63) << 2;
    *(float4*)&yt[c][c4] = *(const float4*)(src + (long long)c * N_ + c4);
  }
  __syncthreads();

  float acc = b2[0];
#pragma unroll
  for (int c = 0; c < 16; ++c) {
    float h = fmaf(yt[c][t], st1[c], st1[16 + c]);
    h = h > 0.f ? h : 0.f;
    acc = fmaf(w2[c], h, acc);
  }
  y2[(long long)b * N_ + n0 + t] = acc;

  float ss = acc, sq = acc * acc;
#pragma unroll
  for (int off = 32; off; off >>= 1) {
    ss += __shfl_down(ss, off, 64);
    sq += __shfl_down(sq, off, 64);
  }
  int wid = t >> 6, lid = t & 63;
  if (lid == 0) { ls[wid] = ss; lq[wid] = sq; }
  __syncthreads();
  if (t == 0) {
    p2[(long long)blockIdx.x * 2 + 0] = (ls[0] + ls[1]) + (ls[2] + ls[3]);
    p2[(long long)blockIdx.x * 2 + 1] = (lq[0] + lq[1]) + (lq[2] + lq[3]);
  }
}

// --------------------------- k_topk ----------------------------------------
// One block per batch, 1024 threads. Thread t holds y2[b, i*1024+t], i<32 as
// sortable u64 keys (monotone float map << 32 | (N-1-idx)); 64 exact argmax
// rounds matching jax.lax.top_k ordering. All key indexing is compile-time
// (rule #20: runtime-indexed reg arrays spill to scratch).
__global__ __launch_bounds__(1024) void k_topk(const float* __restrict__ y2,
                                               const float* __restrict__ p2,
                                               const float* __restrict__ g2,
                                               const float* __restrict__ bt2,
                                               const float* __restrict__ inp,
                                               float* __restrict__ out) {
  __shared__ float rr[1024];
  __shared__ unsigned long long wbest[16];
  __shared__ int   idxs[K_];
  __shared__ float scores[K_];
  __shared__ float s2s[2];

  const int t = threadIdx.x;
  const int b = blockIdx.x;

  // ---- finalize stats2 (identical deterministic computation in every block)
  {
    int comp = t >> 9;                  // 0: sum, 1: sumsq
    int j    = t & 511;
    float a = p2[(long long)(j)        * 2 + comp] +
              p2[(long long)(j + 512)  * 2 + comp] +
              p2[(long long)(j + 1024) * 2 + comp] +
              p2[(long long)(j + 1536) * 2 + comp];
    rr[t] = a;
    __syncthreads();
    for (int s = 256; s > 0; s >>= 1) {
      if (j < s) rr[t] = rr[t] + rr[t + s];
      __syncthreads();
    }
    if (t == 0) {
      const float inv = 1.f / (float)S_;
      float mean = rr[0] * inv;
      float ex2  = rr[512] * inv;
      float var  = ex2 - mean * mean;
      float scv  = g2[0] * rsqrtf(var + EPS_);
      s2s[0] = scv;
      s2s[1] = bt2[0] - mean * scv;
    }
    __syncthreads();
  }
  const float scale2 = s2s[0], shift2 = s2s[1];

  // ---- load keys (rank by raw y2: scale2 > 0 so bn2+relu is monotone,
  //      and top-64 of 32768 N(0,1)-ish values is always strictly positive)
  const float* yrow = y2 + (long long)b * N_;
  unsigned long long key[32];
  unsigned long long cur = 0ull;
#pragma unroll
  for (int i = 0; i < 32; ++i) {
    int idx = (i << 10) | t;
    float v = yrow[idx];
    unsigned u = __float_as_uint(v);
    u = (u & 0x80000000u) ? ~u : (u | 0x80000000u);
    unsigned long long k = ((unsigned long long)u << 32) | (unsigned)(N_ - 1 - idx);
    key[i] = k;
    cur = k > cur ? k : cur;
  }

  const int wid = t >> 6, lid = t & 63;
  for (int r = 0; r < K_; ++r) {
    unsigned long long m = cur;
#pragma unroll
    for (int off = 32; off; off >>= 1) {
      unsigned long long o = __shfl_xor(m, off, 64);
      m = o > m ? o : m;
    }
    if (lid == 0) wbest[wid] = m;
    __syncthreads();
    unsigned long long w = wbest[0];
#pragma unroll
    for (int i = 1; i < 16; ++i) {
      unsigned long long x = wbest[i];
      w = x > w ? x : w;
    }
    const int idx = N_ - 1 - (int)(w & 0xffffffffu);
    if (t == 0) {
      idxs[r] = idx;
      unsigned u = (unsigned)(w >> 32);
      u = (u & 0x80000000u) ? (u & 0x7fffffffu) : ~u;
      float v = __uint_as_float(u);
      float s = fmaf(v, scale2, shift2);
      scores[r] = s > 0.f ? s : 0.f;
    }
    if ((idx & 1023) == t) {
      const int slot = idx >> 10;
#pragma unroll
      for (int i2 = 0; i2 < 32; ++i2)
        if (i2 == slot) key[i2] = 0ull;
      unsigned long long c2 = 0ull;
#pragma unroll
      for (int i2 = 0; i2 < 32; ++i2) c2 = key[i2] > c2 ? key[i2] : c2;
      cur = c2;
    }
    __syncthreads();
  }

  // ---- gather: feat[b, 0:64, k] = input[b, f, idx_k]; feat[b, 64, k] = score_k
  const float* ib = inp + ((long long)b * 64) * N_;
  for (int e = t; e < 65 * 64; e += 1024) {
    int f = e >> 6, k = e & 63;
    float val = (f < 64) ? ib[(long long)f * N_ + idxs[k]] : scores[k];
    out[((long long)b * 65 + f) * 64 + k] = val;
  }
  if (t < K_) out[(long long)B_ * 65 * 64 + b * 64 + t] = (float)idxs[t];
}

// --------------------------- launch ----------------------------------------
extern "C" void kernel_launch(void* const* d_in, const int* in_sizes, int n_in,
                              void* d_out, int out_size, void* d_ws, size_t ws_size,
                              hipStream_t stream) {
  const float* sv  = (const float*)d_in[0];
  const float* inp = (const float*)d_in[1];
  const float* w0  = (const float*)d_in[2];
  const float* b0  = (const float*)d_in[3];
  const float* w1  = (const float*)d_in[4];
  const float* b1  = (const float*)d_in[5];
  const float* w2  = (const float*)d_in[6];
  const float* b2  = (const float*)d_in[7];
  const float* g0  = (const float*)d_in[8];
  const float* bt0 = (const float*)d_in[9];
  const float* g1  = (const float*)d_in[10];
  const float* bt1 = (const float*)d_in[11];
  const float* g2  = (const float*)d_in[12];
  const float* bt2 = (const float*)d_in[13];
  float* out = (float*)d_out;

  float* ws  = (float*)d_ws;
  float* y1  = ws;                                   // S*16     = 8388608
  float* y2  = y1 + (size_t)S_ * 16;                 // S        =  524288
  float* p0  = y2 + (size_t)S_;                      // NB0*128  =  131072
  float* p1  = p0 + (size_t)NB0 * 128;               // NB1*32   =   65536
  float* p2  = p1 + (size_t)NB1 * 32;                // NB2*2    =    4096
  float* st0 = p2 + (size_t)NB2 * 2;                 // 128
  float* st1 = st0 + 128;                            // 32
  float* w0T = st1 + 32;                             // 4096
  float* w1T = w0T + 4096;                           // 1024
  // total ~9.12M floats = ~36.5 MB of workspace

  k_prep   <<<1,    256, 0, stream>>>(w0, w1, w0T, w1T);
  k_stat0  <<<NB0,  256, 0, stream>>>(sv, w0T, b0, p0);
  k_reduce0<<<1,    128, 0, stream>>>(p0, g0, bt0, st0);
  k_layer01<<<NB1,  256, 0, stream>>>(sv, w0T, b0, st0, w1T, b1, y1, p1);
  k_reduce1<<<1,     64, 0, stream>>>(p1, g1, bt1, st1);
  k_layer2 <<<NB2,  256, 0, stream>>>(y1, st1, w2, b2, y2, p2);
  k_topk   <<<B_,  1024, 0, stream>>>(y2, p2, g2, bt2, inp, out);
}

// Round 2
// 279.562 us; speedup vs baseline: 1.1883x; 1.1883x over previous
//
#include <hip/hip_runtime.h>

// ---------------------------------------------------------------------------
// SortNet: 3-layer 1x1-conv MLP (64->64->16->1) with training-mode BatchNorm
// + ReLU, per-batch top-64 over N, gather of input + score.
//
// Pipeline (9 launches + 1 memset, all deterministic):
//   memset     : zero per-batch histogram + candidate counters
//   k_prep     : transpose w0 (64x64) and w1 (16x64)
//   k_stat0    : y0 = w0@sv + b0, per-channel sum/sumsq partials
//   k_reduce0  : finalize scale0/shift0
//   k_layer01  : recompute y0, bn0+relu -> h0, y1 = w1@h0 + b1, stats1 partials
//   k_reduce1  : finalize scale1/shift1
//   k_layer2   : y2 = w2@relu(bn1(y1)) + b2, stats2 partials, PLUS per-batch
//                4096-bin histogram of monotone u32 keys (radix-select pass 1)
//   k_thresh   : per batch, wave suffix-scan of histogram -> threshold bin T
//                with count(key-bin >= T) >= 64
//   k_compact  : compact keys with bin >= T (~64-130 candidates) via atomics
//                (buffer order nondeterministic; final output is exact max
//                 over unique keys -> deterministic)
//   k_final    : 1 wave/batch, no barriers: 64 rounds of in-register wave
//                argmax (jax tie-break: lower index wins), stats2 finalize,
//                score decode, gather feat + idx.
// ---------------------------------------------------------------------------

constexpr int   B_   = 16;
constexpr int   N_   = 32768;
constexpr int   K_   = 64;            // TOP_K
constexpr long long S_ = (long long)B_ * N_;   // 524288
constexpr float EPS_ = 1e-5f;

constexpr int NB0   = 1024;   // k_stat0 blocks
constexpr int NB1   = 2048;   // k_layer01 blocks
constexpr int NB2   = 128;    // k_layer2 / k_compact blocks (4096 pos each)
constexpr int T64   = 8192;   // number of 64-position tiles (S/64)
constexpr int NBINS = 4096;   // radix-select bins (key >> 20)
constexpr int CAP   = 1024;   // candidate capacity per batch

__device__ __forceinline__ unsigned key_map(float f) {
  unsigned u = __float_as_uint(f);
  return (u & 0x80000000u) ? ~u : (u | 0x80000000u);
}

// --------------------------- k_prep ----------------------------------------
__global__ __launch_bounds__(256) void k_prep(const float* __restrict__ w0,
                                              const float* __restrict__ w1,
                                              float* __restrict__ w0T,
                                              float* __restrict__ w1T) {
  int t = threadIdx.x;
  for (int e = t; e < 64 * 64; e += 256) {
    int o = e >> 6, f = e & 63;
    w0T[f * 64 + o] = w0[e];          // w0T[f][o] = w0[o][f]
  }
  for (int e = t; e < 16 * 64; e += 256) {
    int o = e >> 6, c = e & 63;
    w1T[c * 16 + o] = w1[e];          // w1T[c][o] = w1[o][c]
  }
}

// --------------------------- k_stat0 ---------------------------------------
__global__ __launch_bounds__(256) void k_stat0(const float* __restrict__ sv,
                                               const float* __restrict__ w0T,
                                               const float* __restrict__ b0,
                                               float* __restrict__ p0) {
  __shared__ float svt[64][64];
  const int t  = threadIdx.x;
  const int p  = t & 63;
  const int cg = __builtin_amdgcn_readfirstlane(t >> 6);  // wave-uniform

  float bb[16];
#pragma unroll
  for (int j = 0; j < 16; ++j) bb[j] = b0[cg * 16 + j];

  float s1[16], s2[16];
#pragma unroll
  for (int j = 0; j < 16; ++j) { s1[j] = 0.f; s2[j] = 0.f; }

  for (int tile = blockIdx.x; tile < T64; tile += NB0) {
    const int b  = tile >> 9;             // 512 tiles per batch
    const int n0 = (tile & 511) << 6;
    const float* src = sv + ((long long)b * 64) * N_ + n0;
    __syncthreads();
#pragma unroll
    for (int q = 0; q < 4; ++q) {
      int e = t + q * 256;                // 1024 float4 per tile
      int f = e >> 4, c4 = (e & 15) << 2;
      *(float4*)&svt[f][c4] = *(const float4*)(src + (long long)f * N_ + c4);
    }
    __syncthreads();

    float y[16];
#pragma unroll
    for (int j = 0; j < 16; ++j) y[j] = bb[j];
    for (int f = 0; f < 64; ++f) {
      float s = svt[f][p];
      const float* wr = w0T + f * 64 + cg * 16;   // wave-uniform -> s_load
#pragma unroll
      for (int j = 0; j < 16; ++j) y[j] = fmaf(wr[j], s, y[j]);
    }
#pragma unroll
    for (int j = 0; j < 16; ++j) {
      s1[j] += y[j];
      s2[j] = fmaf(y[j], y[j], s2[j]);
    }
  }

#pragma unroll
  for (int j = 0; j < 16; ++j) {
#pragma unroll
    for (int off = 32; off; off >>= 1) {
      s1[j] += __shfl_down(s1[j], off, 64);
      s2[j] += __shfl_down(s2[j], off, 64);
    }
  }
  if (p == 0) {
    float* dst = p0 + (long long)blockIdx.x * 128;
#pragma unroll
    for (int j = 0; j < 16; ++j) {
      dst[cg * 16 + j]      = s1[j];
      dst[64 + cg * 16 + j] = s2[j];
    }
  }
}

// --------------------------- k_reduce0 -------------------------------------
__global__ __launch_bounds__(128) void k_reduce0(const float* __restrict__ p0,
                                                 const float* __restrict__ g,
                                                 const float* __restrict__ bt,
                                                 float* __restrict__ st) {
  __shared__ float l[128];
  int j = threadIdx.x;
  float a0 = 0.f, a1 = 0.f, a2 = 0.f, a3 = 0.f;
  for (int i = 0; i < NB0; i += 4) {
    a0 += p0[(long long)(i + 0) * 128 + j];
    a1 += p0[(long long)(i + 1) * 128 + j];
    a2 += p0[(long long)(i + 2) * 128 + j];
    a3 += p0[(long long)(i + 3) * 128 + j];
  }
  l[j] = (a0 + a1) + (a2 + a3);
  __syncthreads();
  if (j < 64) {
    const float inv = 1.f / (float)S_;
    float mean = l[j] * inv;
    float ex2  = l[64 + j] * inv;
    float var  = ex2 - mean * mean;
    float sc   = g[j] * rsqrtf(var + EPS_);
    st[j]      = sc;
    st[64 + j] = bt[j] - mean * sc;
  }
}

// --------------------------- k_layer01 -------------------------------------
__global__ __launch_bounds__(256) void k_layer01(const float* __restrict__ sv,
                                                 const float* __restrict__ w0T,
                                                 const float* __restrict__ b0,
                                                 const float* __restrict__ st0,
                                                 const float* __restrict__ w1T,
                                                 const float* __restrict__ b1,
                                                 float* __restrict__ y1,
                                                 float* __restrict__ p1) {
  __shared__ float svt[64][64];
  __shared__ float h0[64][64];
  const int t  = threadIdx.x;
  const int p  = t & 63;
  const int cg = __builtin_amdgcn_readfirstlane(t >> 6);

  float bb[16], sc[16], sh[16];
#pragma unroll
  for (int j = 0; j < 16; ++j) {
    bb[j] = b0[cg * 16 + j];
    sc[j] = st0[cg * 16 + j];
    sh[j] = st0[64 + cg * 16 + j];
  }
  float bb1[4];
#pragma unroll
  for (int j = 0; j < 4; ++j) bb1[j] = b1[cg * 4 + j];

  float s1[4], s2[4];
#pragma unroll
  for (int j = 0; j < 4; ++j) { s1[j] = 0.f; s2[j] = 0.f; }

  for (int tile = blockIdx.x; tile < T64; tile += NB1) {
    const int b  = tile >> 9;
    const int n0 = (tile & 511) << 6;
    const float* src = sv + ((long long)b * 64) * N_ + n0;
    __syncthreads();
#pragma unroll
    for (int q = 0; q < 4; ++q) {
      int e = t + q * 256;
      int f = e >> 4, c4 = (e & 15) << 2;
      *(float4*)&svt[f][c4] = *(const float4*)(src + (long long)f * N_ + c4);
    }
    __syncthreads();

    float y[16];
#pragma unroll
    for (int j = 0; j < 16; ++j) y[j] = bb[j];
    for (int f = 0; f < 64; ++f) {
      float s = svt[f][p];
      const float* wr = w0T + f * 64 + cg * 16;
#pragma unroll
      for (int j = 0; j < 16; ++j) y[j] = fmaf(wr[j], s, y[j]);
    }
#pragma unroll
    for (int j = 0; j < 16; ++j) {
      float h = fmaf(y[j], sc[j], sh[j]);
      h0[cg * 16 + j][p] = h > 0.f ? h : 0.f;
    }
    __syncthreads();

    float z[4];
#pragma unroll
    for (int j = 0; j < 4; ++j) z[j] = bb1[j];
    for (int f = 0; f < 64; ++f) {
      float h = h0[f][p];
      const float* wr = w1T + f * 16 + cg * 4;
#pragma unroll
      for (int j = 0; j < 4; ++j) z[j] = fmaf(wr[j], h, z[j]);
    }
#pragma unroll
    for (int j = 0; j < 4; ++j) {
      s1[j] += z[j];
      s2[j] = fmaf(z[j], z[j], s2[j]);
      y1[((long long)b * 16 + cg * 4 + j) * N_ + n0 + p] = z[j];
    }
  }

#pragma unroll
  for (int j = 0; j < 4; ++j) {
#pragma unroll
    for (int off = 32; off; off >>= 1) {
      s1[j] += __shfl_down(s1[j], off, 64);
      s2[j] += __shfl_down(s2[j], off, 64);
    }
  }
  if (p == 0) {
    float* dst = p1 + (long long)blockIdx.x * 32;
#pragma unroll
    for (int j = 0; j < 4; ++j) {
      dst[cg * 4 + j]      = s1[j];
      dst[16 + cg * 4 + j] = s2[j];
    }
  }
}

// --------------------------- k_reduce1 -------------------------------------
__global__ __launch_bounds__(64) void k_reduce1(const float* __restrict__ p1,
                                                const float* __restrict__ g,
                                                const float* __restrict__ bt,
                                                float* __restrict__ st) {
  __shared__ float l[32];
  int j = threadIdx.x;
  if (j < 32) {
    float a0 = 0.f, a1 = 0.f, a2 = 0.f, a3 = 0.f;
    for (int i = 0; i < NB1; i += 4) {
      a0 += p1[(long long)(i + 0) * 32 + j];
      a1 += p1[(long long)(i + 1) * 32 + j];
      a2 += p1[(long long)(i + 2) * 32 + j];
      a3 += p1[(long long)(i + 3) * 32 + j];
    }
    l[j] = (a0 + a1) + (a2 + a3);
  }
  __syncthreads();
  if (j < 16) {
    const float inv = 1.f / (float)S_;
    float mean = l[j] * inv;
    float ex2  = l[16 + j] * inv;
    float var  = ex2 - mean * mean;
    float sc   = g[j] * rsqrtf(var + EPS_);
    st[j]      = sc;
    st[16 + j] = bt[j] - mean * sc;
  }
}

// --------------------------- k_layer2 --------------------------------------
// 128 blocks x 1024 threads; 4 consecutive positions per thread (float4).
// Computes y2, per-block stats2 partials, and the per-batch key histogram.
__global__ __launch_bounds__(1024) void k_layer2(const float* __restrict__ y1,
                                                 const float* __restrict__ st1,
                                                 const float* __restrict__ w2,
                                                 const float* __restrict__ b2,
                                                 float* __restrict__ y2,
                                                 float* __restrict__ p2,
                                                 int* __restrict__ ghist) {
  __shared__ int hist[NBINS];
  __shared__ float ls[16], lq[16];
  const int t   = threadIdx.x;
  const int blk = blockIdx.x;
  const int b   = blk >> 3;
  const int n0  = ((blk & 7) << 12) | (t << 2);   // 4096 positions per block

#pragma unroll
  for (int i = 0; i < NBINS / 1024; ++i) hist[t + i * 1024] = 0;

  float sc[16], sh[16], w[16];
#pragma unroll
  for (int c = 0; c < 16; ++c) { sc[c] = st1[c]; sh[c] = st1[16 + c]; w[c] = w2[c]; }
  const float bias = b2[0];

  float a0 = bias, a1 = bias, a2 = bias, a3 = bias;
  const float* base = y1 + ((long long)b * 16) * N_ + n0;
#pragma unroll
  for (int c = 0; c < 16; ++c) {
    float4 v = *(const float4*)(base + (long long)c * N_);
    float h;
    h = fmaf(v.x, sc[c], sh[c]); h = h > 0.f ? h : 0.f; a0 = fmaf(w[c], h, a0);
    h = fmaf(v.y, sc[c], sh[c]); h = h > 0.f ? h : 0.f; a1 = fmaf(w[c], h, a1);
    h = fmaf(v.z, sc[c], sh[c]); h = h > 0.f ? h : 0.f; a2 = fmaf(w[c], h, a2);
    h = fmaf(v.w, sc[c], sh[c]); h = h > 0.f ? h : 0.f; a3 = fmaf(w[c], h, a3);
  }
  float4 o; o.x = a0; o.y = a1; o.z = a2; o.w = a3;
  *(float4*)(y2 + (long long)b * N_ + n0) = o;

  __syncthreads();   // hist zeroed before any atomic

  atomicAdd(&hist[key_map(a0) >> 20], 1);
  atomicAdd(&hist[key_map(a1) >> 20], 1);
  atomicAdd(&hist[key_map(a2) >> 20], 1);
  atomicAdd(&hist[key_map(a3) >> 20], 1);

  float ss = (a0 + a1) + (a2 + a3);
  float sq = fmaf(a0, a0, fmaf(a1, a1, fmaf(a2, a2, a3 * a3)));
#pragma unroll
  for (int off = 32; off; off >>= 1) {
    ss += __shfl_down(ss, off, 64);
    sq += __shfl_down(sq, off, 64);
  }
  const int wid = t >> 6, lid = t & 63;
  if (lid == 0) { ls[wid] = ss; lq[wid] = sq; }
  __syncthreads();   // covers ls/lq stores AND hist atomics
  if (t == 0) {
    float Sv = 0.f, Qv = 0.f;
#pragma unroll
    for (int i = 0; i < 16; ++i) { Sv += ls[i]; Qv += lq[i]; }
    p2[blk * 2 + 0] = Sv;
    p2[blk * 2 + 1] = Qv;
  }
#pragma unroll
  for (int i = 0; i < NBINS / 1024; ++i) {
    int v = hist[t + i * 1024];
    if (v) atomicAdd(&ghist[b * NBINS + t + i * 1024], v);
  }
}

// --------------------------- k_thresh --------------------------------------
// One block per batch. Wave 0 suffix-scans the 4096-bin histogram to find
// T = max bin with count(bin >= T) >= 64.
__global__ __launch_bounds__(256) void k_thresh(const int* __restrict__ ghist,
                                                int* __restrict__ Tb) {
  __shared__ int hl[NBINS + NBINS / 64];   // +1 word pad per 64 (bank spread)
  const int t = threadIdx.x, b = blockIdx.x;
  const int* h = ghist + b * NBINS;
  for (int i = t; i < NBINS; i += 256) hl[i + (i >> 6)] = h[i];
  __syncthreads();
  if (t < 64) {
    const int l = t;
    int s = 0;
    for (int j = 0; j < 64; ++j) s += hl[(l * 64 + j) + l];
    int Sv = s;                           // suffix over chunks
#pragma unroll
    for (int off = 1; off < 64; off <<= 1) {
      int v = __shfl_down(Sv, off, 64);
      if (l + off < 64) Sv += v;
    }
    unsigned long long m = __ballot(Sv >= K_);
    const int lstar = 63 - __builtin_clzll(m);
    const int tailS = (lstar < 63) ? __shfl(Sv, lstar + 1, 64) : 0;
    int Tj = hl[(lstar * 64 + l) + lstar];
#pragma unroll
    for (int off = 1; off < 64; off <<= 1) {
      int v = __shfl_down(Tj, off, 64);
      if (l + off < 64) Tj += v;
    }
    const int cge = Tj + tailS;
    unsigned long long m2 = __ballot(cge >= K_);
    const int jstar = 63 - __builtin_clzll(m2);
    if (l == 0) Tb[b] = lstar * 64 + jstar;
  }
}

// --------------------------- k_compact -------------------------------------
__global__ __launch_bounds__(1024) void k_compact(const float* __restrict__ y2,
                                                  const int* __restrict__ Tb,
                                                  int* __restrict__ cnt,
                                                  unsigned long long* __restrict__ cand) {
  const int t = threadIdx.x, blk = blockIdx.x;
  const int b  = blk >> 3;
  const int n0 = ((blk & 7) << 12) | (t << 2);
  const int T  = Tb[b];
  float4 v = *(const float4*)(y2 + (long long)b * N_ + n0);
  unsigned long long* cb = cand + (long long)b * CAP;
#define DO_CAND(comp, off)                                                    \
  {                                                                           \
    unsigned u = key_map(comp);                                               \
    if ((int)(u >> 20) >= T) {                                                \
      int slot = atomicAdd(&cnt[b], 1);                                       \
      if (slot < CAP)                                                         \
        cb[slot] = ((unsigned long long)u << 32) |                            \
                   (unsigned)(N_ - 1 - (n0 + off));                           \
    }                                                                         \
  }
  DO_CAND(v.x, 0) DO_CAND(v.y, 1) DO_CAND(v.z, 2) DO_CAND(v.w, 3)
#undef DO_CAND
}

// --------------------------- k_final ---------------------------------------
// 1 wave per batch, zero barriers. stats2 finalize (deterministic, identical
// in every block), 64 rounds of in-register wave argmax, score decode, gather.
__global__ __launch_bounds__(64) void k_final(const unsigned long long* __restrict__ cand,
                                              const int* __restrict__ cnt,
                                              const float* __restrict__ p2,
                                              const float* __restrict__ g2,
                                              const float* __restrict__ bt2,
                                              const float* __restrict__ inp,
                                              float* __restrict__ out) {
  const int b = blockIdx.x, l = threadIdx.x;

  // stats2 from 128 block partials (fixed-order tree, same in all blocks)
  float s1 = p2[2 * l] + p2[2 * (l + 64)];
  float q1 = p2[2 * l + 1] + p2[2 * (l + 64) + 1];
#pragma unroll
  for (int off = 32; off; off >>= 1) {
    s1 += __shfl_down(s1, off, 64);
    q1 += __shfl_down(q1, off, 64);
  }
  s1 = __shfl(s1, 0, 64);
  q1 = __shfl(q1, 0, 64);
  const float inv = 1.f / (float)S_;
  const float mean = s1 * inv;
  const float var  = q1 * inv - mean * mean;
  const float scale2 = g2[0] * rsqrtf(var + EPS_);
  const float shift2 = bt2[0] - mean * scale2;

  int cn = cnt[b];
  if (cn > CAP) cn = CAP;
  const unsigned long long* cb = cand + (long long)b * CAP;
  unsigned long long k[16];
#pragma unroll
  for (int r = 0; r < 16; ++r) {
    int i = l + r * 64;
    k[r] = (i < cn) ? cb[i] : 0ull;
  }
  unsigned long long cur = 0ull;
#pragma unroll
  for (int r = 0; r < 16; ++r) cur = k[r] > cur ? k[r] : cur;

  int myidx = 0;
  unsigned mymap = 0;
  for (int r = 0; r < K_; ++r) {
    unsigned long long m = cur;
#pragma unroll
    for (int off = 32; off; off >>= 1) {
      unsigned long long o = __shfl_xor(m, off, 64);
      m = o > m ? o : m;
    }
    if (r == l) {
      myidx = N_ - 1 - (int)(m & 0xffffffffu);
      mymap = (unsigned)(m >> 32);
    }
    if (cur == m) {          // exactly one lane (keys unique)
#pragma unroll
      for (int r2 = 0; r2 < 16; ++r2)
        if (k[r2] == m) k[r2] = 0ull;
      unsigned long long c2 = 0ull;
#pragma unroll
      for (int r2 = 0; r2 < 16; ++r2) c2 = k[r2] > c2 ? k[r2] : c2;
      cur = c2;
    }
  }

  unsigned u = mymap;
  u = (u & 0x80000000u) ? (u & 0x7fffffffu) : ~u;
  float v = __uint_as_float(u);
  float scv = fmaf(v, scale2, shift2);
  scv = scv > 0.f ? scv : 0.f;

  const float* ib = inp + ((long long)b * 64) * N_;
#pragma unroll 4
  for (int f = 0; f < 64; ++f)
    out[((long long)b * 65 + f) * 64 + l] = ib[(long long)f * N_ + myidx];
  out[((long long)b * 65 + 64) * 64 + l] = scv;
  out[(long long)B_ * 65 * 64 + b * 64 + l] = (float)myidx;
}

// --------------------------- launch ----------------------------------------
extern "C" void kernel_launch(void* const* d_in, const int* in_sizes, int n_in,
                              void* d_out, int out_size, void* d_ws, size_t ws_size,
                              hipStream_t stream) {
  const float* sv  = (const float*)d_in[0];
  const float* inp = (const float*)d_in[1];
  const float* w0  = (const float*)d_in[2];
  const float* b0  = (const float*)d_in[3];
  const float* w1  = (const float*)d_in[4];
  const float* b1  = (const float*)d_in[5];
  const float* w2  = (const float*)d_in[6];
  const float* b2  = (const float*)d_in[7];
  const float* g0  = (const float*)d_in[8];
  const float* bt0 = (const float*)d_in[9];
  const float* g1  = (const float*)d_in[10];
  const float* bt1 = (const float*)d_in[11];
  const float* g2  = (const float*)d_in[12];
  const float* bt2 = (const float*)d_in[13];
  float* out = (float*)d_out;

  float* ws  = (float*)d_ws;
  float* y1  = ws;                                    // 8388608 floats
  float* y2  = y1 + (size_t)S_ * 16;                  //  524288
  float* p0  = y2 + (size_t)S_;                       //  131072
  float* p1  = p0 + (size_t)NB0 * 128;                //   65536
  float* p2  = p1 + (size_t)NB1 * 32;                 //     256
  float* st0 = p2 + 256;                              //     128
  float* st1 = st0 + 128;                             //      32
  float* w0T = st1 + 32;                              //    4096
  float* w1T = w0T + 4096;                            //    1024
  int*   ghist = (int*)(w1T + 1024);                  //   65536 ints
  int*   cnt   = ghist + (size_t)B_ * NBINS;          //      16 ints
  int*   Tb    = cnt + 16;                            //      16 ints
  unsigned long long* cand =
      (unsigned long long*)(Tb + 16);                 // 16*CAP u64 (8B-aligned)

  hipMemsetAsync(ghist, 0, ((size_t)B_ * NBINS + 16) * sizeof(int), stream);

  k_prep   <<<1,    256, 0, stream>>>(w0, w1, w0T, w1T);
  k_stat0  <<<NB0,  256, 0, stream>>>(sv, w0T, b0, p0);
  k_reduce0<<<1,    128, 0, stream>>>(p0, g0, bt0, st0);
  k_layer01<<<NB1,  256, 0, stream>>>(sv, w0T, b0, st0, w1T, b1, y1, p1);
  k_reduce1<<<1,     64, 0, stream>>>(p1, g1, bt1, st1);
  k_layer2 <<<NB2, 1024, 0, stream>>>(y1, st1, w2, b2, y2, p2, ghist);
  k_thresh <<<B_,   256, 0, stream>>>(ghist, Tb);
  k_compact<<<NB2, 1024, 0, stream>>>(y2, Tb, cnt, cand);
  k_final  <<<B_,    64, 0, stream>>>(cand, cnt, p2, g2, bt2, inp, out);
}